// Round 7
// baseline (308.469 us; speedup 1.0000x reference)
//
#include <hip/hip_runtime.h>
#include <hip/hip_bf16.h>

// RoutingLayer: B=128,S=64,N=32, D=128, K=8 capsules x C=16, 3 routing iters.
// R7: ZERO-LDS register-resident routing. MFMA C/D layout (row=(q,r) regs,
// col=ml lanes) is kept end-to-end: capsule reductions = 16-lane DPP sums,
// softmax over k = in-lane over 8 regs (|logit|<=1, no max needed), n-sums =
// in-lane + 2 cross-quad shuffles. Self-row z computed by a pre-kernel into
// d_out (read then overwritten by routing). Split-bf16 GEMM as before.

#define DD 128

typedef __attribute__((ext_vector_type(8))) short bf16x8;
typedef __attribute__((ext_vector_type(4))) float f32x4;
typedef __attribute__((ext_vector_type(4))) float float4v;

__device__ __forceinline__ float bf16bits_to_f32(unsigned short u) {
  return __uint_as_float(((unsigned int)u) << 16);
}
__device__ __forceinline__ void split_bf16(float x, unsigned short& hi, unsigned short& lo) {
  unsigned int xb = __float_as_uint(x);
  hi = (unsigned short)(xb >> 16);
  float hif = __uint_as_float(xb & 0xFFFF0000u);
  float lof = x - hif;  // exact
  lo = (unsigned short)(__float_as_uint(lof) >> 16);
}
__device__ __forceinline__ void make_frag(float4v v0, float4v v1, bf16x8& h, bf16x8& l) {
#pragma unroll
  for (int i = 0; i < 4; ++i) {
    unsigned short hh, ll;
    split_bf16(v0[i], hh, ll);
    h[i] = (short)hh; l[i] = (short)ll;
    split_bf16(v1[i], hh, ll);
    h[4 + i] = (short)hh; l[4 + i] = (short)ll;
  }
}

// DPP-fused add: x + dpp_perm(x). Stays on the VALU pipe (no DS traffic).
template <int CTRL>
__device__ __forceinline__ float dpp_add(float x) {
  int y = __builtin_amdgcn_update_dpp(0, __float_as_int(x), CTRL, 0xf, 0xf, true);
  return x + __int_as_float(y);
}
// Full sum over the 16 lanes of a row (result replicated to all 16).
__device__ __forceinline__ float sum16(float x) {
  x = dpp_add<0xB1>(x);   // quad_perm [1,0,3,2]  (xor 1)
  x = dpp_add<0x4E>(x);   // quad_perm [2,3,0,1]  (xor 2)
  x = dpp_add<0x124>(x);  // row_ror:4
  x = dpp_add<0x128>(x);  // row_ror:8
  return x;
}

__device__ __forceinline__ unsigned pack_bf16(float a, float b) {
  return (__float_as_uint(a) >> 16) | (__float_as_uint(b) & 0xFFFF0000u);
}
__device__ __forceinline__ float unpack_lo(unsigned w) {
  return __uint_as_float(w << 16);
}
__device__ __forceinline__ float unpack_hi(unsigned w) {
  return __uint_as_float(w & 0xFFFF0000u);
}

__global__ void detect_kernel(const unsigned short* __restrict__ w1u,
                              int* __restrict__ flag) {
  int t = threadIdx.x;
  float v = bf16bits_to_f32(w1u[2 * t]);
  int hit = !(fabsf(v) < 1e4f);
  unsigned long long m = __ballot(hit);
  if (t == 0) flag[0] = (m != 0ull) ? 1 : 0;
}

// W (k-major 128x128) -> MFMA-B fragment-major hi/lo bf16.
__global__ __launch_bounds__(256) void swizzle_w_kernel(
    const void* __restrict__ w1, const int* __restrict__ flag,
    unsigned short* __restrict__ whi, unsigned short* __restrict__ wlo) {
  int idx = blockIdx.x * 256 + threadIdx.x;
  int k = idx >> 7, n = idx & 127;
  int kt = k >> 5, q = (k >> 3) & 3, j = k & 7;
  int nt = n >> 4, nl = n & 15;
  int lane = q * 16 + nl;
  int dst = ((kt * 8 + nt) * 64 + lane) * 8 + j;
  unsigned short hb, lb;
  if (*flag) {
    split_bf16(((const float*)w1)[idx], hb, lb);
  } else {
    hb = ((const unsigned short*)w1)[idx];
    lb = 0;
  }
  whi[dst] = hb;
  wlo[dst] = lb;
}

// Self z: 16 nodes per wave. zhat_self (normalized) written to OUT (the routing
// kernel reads it, then overwrites the same row with the final result).
__global__ __launch_bounds__(64, 4) void selfz_kernel(
    const void* __restrict__ selfv,
    const unsigned short* __restrict__ whi,
    const unsigned short* __restrict__ wlo,
    const void* __restrict__ b1,
    void* __restrict__ out,
    const int* __restrict__ flag) {
  const int lane = threadIdx.x;
  const int q = lane >> 4, ml = lane & 15;
  const int base = blockIdx.x * 16;  // 512 blocks x 16 rows
  const bool isf32 = (*flag != 0);

  f32x4 acc[8];
#pragma unroll
  for (int nt = 0; nt < 8; ++nt) acc[nt] = (f32x4){0.f, 0.f, 0.f, 0.f};

#pragma unroll
  for (int kt = 0; kt < 4; ++kt) {
    const int col = kt * 32 + q * 8;
    bf16x8 ah, al;
    if (isf32) {
      const float* sf = (const float*)selfv + (size_t)(base + ml) * DD + col;
      make_frag(*(const float4v*)sf, *(const float4v*)(sf + 4), ah, al);
    } else {
      ah = *(const bf16x8*)((const unsigned short*)selfv + (size_t)(base + ml) * DD + col);
      al = (bf16x8){0, 0, 0, 0, 0, 0, 0, 0};
    }
#pragma unroll
    for (int nt = 0; nt < 8; ++nt) {
      const size_t bo = ((size_t)(kt * 8 + nt) * 64 + lane) * 8;
      bf16x8 bh = *(const bf16x8*)(whi + bo);
      bf16x8 bl = *(const bf16x8*)(wlo + bo);
      acc[nt] = __builtin_amdgcn_mfma_f32_16x16x32_bf16(ah, bh, acc[nt], 0, 0, 0);
      acc[nt] = __builtin_amdgcn_mfma_f32_16x16x32_bf16(ah, bl, acc[nt], 0, 0, 0);
      acc[nt] = __builtin_amdgcn_mfma_f32_16x16x32_bf16(al, bh, acc[nt], 0, 0, 0);
    }
  }
  // bias + relu, then per-capsule normalize (reduce over ml lanes).
#pragma unroll
  for (int nt = 0; nt < 8; ++nt) {
    const float bv = isf32 ? ((const float*)b1)[nt * 16 + ml]
                           : bf16bits_to_f32(((const unsigned short*)b1)[nt * 16 + ml]);
#pragma unroll
    for (int r = 0; r < 4; ++r) acc[nt][r] = fmaxf(acc[nt][r] + bv, 0.f);
  }
#pragma unroll
  for (int r = 0; r < 4; ++r)
#pragma unroll
    for (int nt = 0; nt < 8; ++nt) {
      float ss = sum16(acc[nt][r] * acc[nt][r]);
      acc[nt][r] *= 1.f / fmaxf(sqrtf(ss), 1e-12f);
    }
  // store: row g = base + q*4 + r, col nt*16+ml
#pragma unroll
  for (int r = 0; r < 4; ++r)
#pragma unroll
    for (int nt = 0; nt < 8; ++nt) {
      const size_t o = (size_t)(base + q * 4 + r) * DD + nt * 16 + ml;
      if (isf32) {
        ((float*)out)[o] = acc[nt][r];
      } else {
        unsigned int xb = __float_as_uint(acc[nt][r]);
        ((unsigned short*)out)[o] =
            (unsigned short)((xb + 0x7fffu + ((xb >> 16) & 1u)) >> 16);
      }
    }
}

__global__ __launch_bounds__(64, 4) void routing_kernel(
    const void* __restrict__ neighv,
    const unsigned short* __restrict__ whi,
    const unsigned short* __restrict__ wlo,
    const void* __restrict__ b1,
    void* __restrict__ out,   // in: zhat_self ; out: final result
    const int* __restrict__ flag) {
  const int lane = threadIdx.x;
  const int q = lane >> 4, ml = lane & 15;
  const size_t bs = blockIdx.x;
  const bool isf32 = (*flag != 0);

  // zhat_self for this node (written by selfz_kernel into out).
  float zs[8];
#pragma unroll
  for (int nt = 0; nt < 8; ++nt) {
    const size_t o = bs * DD + nt * 16 + ml;
    zs[nt] = isf32 ? ((const float*)out)[o]
                   : bf16bits_to_f32(((const unsigned short*)out)[o]);
  }

  // ---------------- neighbor GEMM: acc[mt][nt], rows mt*16+q*4+r, col nt*16+ml
  f32x4 acc[2][8];
#pragma unroll
  for (int mt = 0; mt < 2; ++mt)
#pragma unroll
    for (int nt = 0; nt < 8; ++nt) acc[mt][nt] = (f32x4){0.f, 0.f, 0.f, 0.f};

  const size_t noff = bs * (size_t)(32 * DD);
#pragma unroll
  for (int kt = 0; kt < 4; ++kt) {
    const int col = kt * 32 + q * 8;
    bf16x8 a0h, a0l, a1h, a1l;
    if (isf32) {
      const float* nf = (const float*)neighv + noff;
      const float* p0 = nf + (size_t)ml * DD + col;
      const float* p1 = nf + (size_t)(16 + ml) * DD + col;
      make_frag(*(const float4v*)p0, *(const float4v*)(p0 + 4), a0h, a0l);
      make_frag(*(const float4v*)p1, *(const float4v*)(p1 + 4), a1h, a1l);
    } else {
      const unsigned short* nbf = (const unsigned short*)neighv + noff;
      a0h = *(const bf16x8*)(nbf + (size_t)ml * DD + col);
      a1h = *(const bf16x8*)(nbf + (size_t)(16 + ml) * DD + col);
      a0l = (bf16x8){0, 0, 0, 0, 0, 0, 0, 0};
      a1l = a0l;
    }
#pragma unroll
    for (int nt = 0; nt < 8; ++nt) {
      const size_t bo = ((size_t)(kt * 8 + nt) * 64 + lane) * 8;
      bf16x8 bh = *(const bf16x8*)(whi + bo);
      bf16x8 bl = *(const bf16x8*)(wlo + bo);
      acc[0][nt] = __builtin_amdgcn_mfma_f32_16x16x32_bf16(a0h, bh, acc[0][nt], 0, 0, 0);
      acc[1][nt] = __builtin_amdgcn_mfma_f32_16x16x32_bf16(a1h, bh, acc[1][nt], 0, 0, 0);
      acc[0][nt] = __builtin_amdgcn_mfma_f32_16x16x32_bf16(a0h, bl, acc[0][nt], 0, 0, 0);
      acc[1][nt] = __builtin_amdgcn_mfma_f32_16x16x32_bf16(a1h, bl, acc[1][nt], 0, 0, 0);
      acc[0][nt] = __builtin_amdgcn_mfma_f32_16x16x32_bf16(a0l, bh, acc[0][nt], 0, 0, 0);
      acc[1][nt] = __builtin_amdgcn_mfma_f32_16x16x32_bf16(a1l, bh, acc[1][nt], 0, 0, 0);
    }
  }

  // bias + relu, then normalize capsules IN PLACE (acc becomes zhat).
#pragma unroll
  for (int nt = 0; nt < 8; ++nt) {
    const float bv = isf32 ? ((const float*)b1)[nt * 16 + ml]
                           : bf16bits_to_f32(((const unsigned short*)b1)[nt * 16 + ml]);
#pragma unroll
    for (int mt = 0; mt < 2; ++mt)
#pragma unroll
      for (int r = 0; r < 4; ++r) acc[mt][nt][r] = fmaxf(acc[mt][nt][r] + bv, 0.f);
  }
#pragma unroll
  for (int mt = 0; mt < 2; ++mt)
#pragma unroll
    for (int r = 0; r < 4; ++r)
#pragma unroll
      for (int nt = 0; nt < 8; ++nt) {
        float ss = sum16(acc[mt][nt][r] * acc[mt][nt][r]);
        acc[mt][nt][r] *= 1.f / fmaxf(sqrtf(ss), 1e-12f);
      }

  // ---------------- iter 0: u = (1/8) sum_n zhat_n + zs ; normalize ----------
  float u[8];
#pragma unroll
  for (int nt = 0; nt < 8; ++nt) {
    float t = acc[0][nt][0] + acc[0][nt][1] + acc[0][nt][2] + acc[0][nt][3] +
              acc[1][nt][0] + acc[1][nt][1] + acc[1][nt][2] + acc[1][nt][3];
    t += __shfl_xor(t, 16);
    t += __shfl_xor(t, 32);
    u[nt] = t * 0.125f + zs[nt];
  }
#pragma unroll
  for (int nt = 0; nt < 8; ++nt) {
    float ss = sum16(u[nt] * u[nt]);
    u[nt] *= 1.f / fmaxf(sqrtf(ss), 1e-12f);
  }

  // ---------------- iters 1,2 ----------------
  unsigned wp[2][4][4];  // p (prob) bf16-packed: [mt][r][k-pair]
#pragma unroll
  for (int it = 1; it < 3; ++it) {
    // pass1: logits = zhat . u (16-lane DPP sum); in-lane softmax over k.
    // |logit| <= 1 (both unit per capsule) -> exp safe without max-subtract.
#pragma unroll
    for (int mt = 0; mt < 2; ++mt)
#pragma unroll
      for (int r = 0; r < 4; ++r) {
        float e[8];
        float s = 0.f;
#pragma unroll
        for (int nt = 0; nt < 8; ++nt) {
          float l = sum16(acc[mt][nt][r] * u[nt]);
          e[nt] = __expf(l);
          s += e[nt];
        }
        const float inv = 1.f / s;
#pragma unroll
        for (int j = 0; j < 4; ++j)
          wp[mt][r][j] = pack_bf16(e[2 * j] * inv, e[2 * j + 1] * inv);
      }
    // pass2: u[k][c] = sum_n p[n][k] zhat[n][k*16+c] + zs.
#pragma unroll
    for (int nt = 0; nt < 8; ++nt) {
      float t = 0.f;
#pragma unroll
      for (int mt = 0; mt < 2; ++mt)
#pragma unroll
        for (int r = 0; r < 4; ++r) {
          const unsigned w = wp[mt][r][nt >> 1];
          const float p = (nt & 1) ? unpack_hi(w) : unpack_lo(w);
          t = fmaf(p, acc[mt][nt][r], t);
        }
      t += __shfl_xor(t, 16);
      t += __shfl_xor(t, 32);
      u[nt] = t + zs[nt];
    }
    if (it < 2) {
#pragma unroll
      for (int nt = 0; nt < 8; ++nt) {
        float ss = sum16(u[nt] * u[nt]);
        u[nt] *= 1.f / fmaxf(sqrtf(ss), 1e-12f);
      }
    }
  }

  // ---------------- output: relu(u), q==0 lanes write the 128 cols ----------
  if (q == 0) {
#pragma unroll
    for (int nt = 0; nt < 8; ++nt) {
      float r = (u[nt] < 0.f) ? 0.f : u[nt];
      const size_t o = bs * DD + nt * 16 + ml;
      if (isf32) {
        ((float*)out)[o] = r;
      } else {
        unsigned int xb = __float_as_uint(r);
        ((unsigned short*)out)[o] =
            (unsigned short)((xb + 0x7fffu + ((xb >> 16) & 1u)) >> 16);
      }
    }
  }
}

extern "C" void kernel_launch(void* const* d_in, const int* in_sizes, int n_in,
                              void* d_out, int out_size, void* d_ws, size_t ws_size,
                              hipStream_t stream) {
  (void)in_sizes; (void)n_in; (void)out_size; (void)ws_size;
  const void* selfv = d_in[0];
  const void* neighv = d_in[1];
  const void* w1 = d_in[2];
  const void* b1 = d_in[3];
  int* flag = (int*)d_ws;
  unsigned short* whi = (unsigned short*)((char*)d_ws + 64);
  unsigned short* wlo = (unsigned short*)((char*)d_ws + 64 + 32768);

  detect_kernel<<<1, 64, 0, stream>>>((const unsigned short*)w1, flag);
  swizzle_w_kernel<<<64, 256, 0, stream>>>(w1, flag, whi, wlo);
  selfz_kernel<<<512, 64, 0, stream>>>(selfv, whi, wlo, b1, d_out, flag);
  routing_kernel<<<8192, 64, 0, stream>>>(neighv, whi, wlo, b1, d_out, flag);
}

// Round 8
// 298.773 us; speedup vs baseline: 1.0325x; 1.0325x over previous
//
#include <hip/hip_runtime.h>
#include <hip/hip_bf16.h>

// RoutingLayer: B=128,S=64,N=32, D=128, K=8 capsules x C=16, 3 routing iters.
// R8: register-resident routing (zero LDS), spill-free. R7 spilled ~80 VGPRs
// (WRITE_SIZE 169 MB of scratch) because launch_bounds(64,4) capped the
// allocator below the ~140-reg live set. Fixes: (a) pass1+pass2 fused so the
// probability matrix is never stored (saves 32 VGPRs, restores fp32 p);
// (b) launch_bounds(64,3) -> 170-reg cap, no spill.

#define DD 128

typedef __attribute__((ext_vector_type(8))) short bf16x8;
typedef __attribute__((ext_vector_type(4))) float f32x4;
typedef __attribute__((ext_vector_type(4))) float float4v;

__device__ __forceinline__ float bf16bits_to_f32(unsigned short u) {
  return __uint_as_float(((unsigned int)u) << 16);
}
__device__ __forceinline__ void split_bf16(float x, unsigned short& hi, unsigned short& lo) {
  unsigned int xb = __float_as_uint(x);
  hi = (unsigned short)(xb >> 16);
  float hif = __uint_as_float(xb & 0xFFFF0000u);
  float lof = x - hif;  // exact
  lo = (unsigned short)(__float_as_uint(lof) >> 16);
}
__device__ __forceinline__ void make_frag(float4v v0, float4v v1, bf16x8& h, bf16x8& l) {
#pragma unroll
  for (int i = 0; i < 4; ++i) {
    unsigned short hh, ll;
    split_bf16(v0[i], hh, ll);
    h[i] = (short)hh; l[i] = (short)ll;
    split_bf16(v1[i], hh, ll);
    h[4 + i] = (short)hh; l[4 + i] = (short)ll;
  }
}

// DPP-fused add: x + dpp_perm(x). VALU pipe only.
template <int CTRL>
__device__ __forceinline__ float dpp_add(float x) {
  int y = __builtin_amdgcn_update_dpp(0, __float_as_int(x), CTRL, 0xf, 0xf, true);
  return x + __int_as_float(y);
}
// Sum over the 16 lanes of a row (result replicated to all 16).
__device__ __forceinline__ float sum16(float x) {
  x = dpp_add<0xB1>(x);   // quad_perm xor 1
  x = dpp_add<0x4E>(x);   // quad_perm xor 2
  x = dpp_add<0x124>(x);  // row_ror:4
  x = dpp_add<0x128>(x);  // row_ror:8
  return x;
}

__global__ void detect_kernel(const unsigned short* __restrict__ w1u,
                              int* __restrict__ flag) {
  int t = threadIdx.x;
  float v = bf16bits_to_f32(w1u[2 * t]);
  int hit = !(fabsf(v) < 1e4f);
  unsigned long long m = __ballot(hit);
  if (t == 0) flag[0] = (m != 0ull) ? 1 : 0;
}

// W (k-major 128x128) -> MFMA-B fragment-major hi/lo bf16.
__global__ __launch_bounds__(256) void swizzle_w_kernel(
    const void* __restrict__ w1, const int* __restrict__ flag,
    unsigned short* __restrict__ whi, unsigned short* __restrict__ wlo) {
  int idx = blockIdx.x * 256 + threadIdx.x;
  int k = idx >> 7, n = idx & 127;
  int kt = k >> 5, q = (k >> 3) & 3, j = k & 7;
  int nt = n >> 4, nl = n & 15;
  int lane = q * 16 + nl;
  int dst = ((kt * 8 + nt) * 64 + lane) * 8 + j;
  unsigned short hb, lb;
  if (*flag) {
    split_bf16(((const float*)w1)[idx], hb, lb);
  } else {
    hb = ((const unsigned short*)w1)[idx];
    lb = 0;
  }
  whi[dst] = hb;
  wlo[dst] = lb;
}

// Self z: 16 nodes per wave; zhat_self (normalized) -> OUT (routing reads it,
// then overwrites the same row with the final result).
__global__ __launch_bounds__(64, 4) void selfz_kernel(
    const void* __restrict__ selfv,
    const unsigned short* __restrict__ whi,
    const unsigned short* __restrict__ wlo,
    const void* __restrict__ b1,
    void* __restrict__ out,
    const int* __restrict__ flag) {
  const int lane = threadIdx.x;
  const int q = lane >> 4, ml = lane & 15;
  const int base = blockIdx.x * 16;  // 512 blocks x 16 rows
  const bool isf32 = (*flag != 0);

  f32x4 acc[8];
#pragma unroll
  for (int nt = 0; nt < 8; ++nt) acc[nt] = (f32x4){0.f, 0.f, 0.f, 0.f};

#pragma unroll
  for (int kt = 0; kt < 4; ++kt) {
    const int col = kt * 32 + q * 8;
    bf16x8 ah, al;
    if (isf32) {
      const float* sf = (const float*)selfv + (size_t)(base + ml) * DD + col;
      make_frag(*(const float4v*)sf, *(const float4v*)(sf + 4), ah, al);
    } else {
      ah = *(const bf16x8*)((const unsigned short*)selfv + (size_t)(base + ml) * DD + col);
      al = (bf16x8){0, 0, 0, 0, 0, 0, 0, 0};
    }
#pragma unroll
    for (int nt = 0; nt < 8; ++nt) {
      const size_t bo = ((size_t)(kt * 8 + nt) * 64 + lane) * 8;
      bf16x8 bh = *(const bf16x8*)(whi + bo);
      bf16x8 bl = *(const bf16x8*)(wlo + bo);
      acc[nt] = __builtin_amdgcn_mfma_f32_16x16x32_bf16(ah, bh, acc[nt], 0, 0, 0);
      acc[nt] = __builtin_amdgcn_mfma_f32_16x16x32_bf16(ah, bl, acc[nt], 0, 0, 0);
      acc[nt] = __builtin_amdgcn_mfma_f32_16x16x32_bf16(al, bh, acc[nt], 0, 0, 0);
    }
  }
#pragma unroll
  for (int nt = 0; nt < 8; ++nt) {
    const float bv = isf32 ? ((const float*)b1)[nt * 16 + ml]
                           : bf16bits_to_f32(((const unsigned short*)b1)[nt * 16 + ml]);
#pragma unroll
    for (int r = 0; r < 4; ++r) acc[nt][r] = fmaxf(acc[nt][r] + bv, 0.f);
  }
#pragma unroll
  for (int r = 0; r < 4; ++r)
#pragma unroll
    for (int nt = 0; nt < 8; ++nt) {
      float ss = sum16(acc[nt][r] * acc[nt][r]);
      acc[nt][r] *= 1.f / fmaxf(sqrtf(ss), 1e-12f);
    }
#pragma unroll
  for (int r = 0; r < 4; ++r)
#pragma unroll
    for (int nt = 0; nt < 8; ++nt) {
      const size_t o = (size_t)(base + q * 4 + r) * DD + nt * 16 + ml;
      if (isf32) {
        ((float*)out)[o] = acc[nt][r];
      } else {
        unsigned int xb = __float_as_uint(acc[nt][r]);
        ((unsigned short*)out)[o] =
            (unsigned short)((xb + 0x7fffu + ((xb >> 16) & 1u)) >> 16);
      }
    }
}

__global__ __launch_bounds__(64, 3) void routing_kernel(
    const void* __restrict__ neighv,
    const unsigned short* __restrict__ whi,
    const unsigned short* __restrict__ wlo,
    const void* __restrict__ b1,
    void* __restrict__ out,   // in: zhat_self ; out: final result
    const int* __restrict__ flag) {
  const int lane = threadIdx.x;
  const int q = lane >> 4, ml = lane & 15;
  const size_t bs = blockIdx.x;
  const bool isf32 = (*flag != 0);

  // zhat_self for this node (written by selfz_kernel into out).
  float zs[8];
#pragma unroll
  for (int nt = 0; nt < 8; ++nt) {
    const size_t o = bs * DD + nt * 16 + ml;
    zs[nt] = isf32 ? ((const float*)out)[o]
                   : bf16bits_to_f32(((const unsigned short*)out)[o]);
  }

  // ---- neighbor GEMM: acc[mt][nt], rows mt*16+q*4+r, col nt*16+ml ----------
  f32x4 acc[2][8];
#pragma unroll
  for (int mt = 0; mt < 2; ++mt)
#pragma unroll
    for (int nt = 0; nt < 8; ++nt) acc[mt][nt] = (f32x4){0.f, 0.f, 0.f, 0.f};

  const size_t noff = bs * (size_t)(32 * DD);
#pragma unroll
  for (int kt = 0; kt < 4; ++kt) {
    const int col = kt * 32 + q * 8;
    bf16x8 a0h, a0l, a1h, a1l;
    if (isf32) {
      const float* nf = (const float*)neighv + noff;
      const float* p0 = nf + (size_t)ml * DD + col;
      const float* p1 = nf + (size_t)(16 + ml) * DD + col;
      make_frag(*(const float4v*)p0, *(const float4v*)(p0 + 4), a0h, a0l);
      make_frag(*(const float4v*)p1, *(const float4v*)(p1 + 4), a1h, a1l);
    } else {
      const unsigned short* nbf = (const unsigned short*)neighv + noff;
      a0h = *(const bf16x8*)(nbf + (size_t)ml * DD + col);
      a1h = *(const bf16x8*)(nbf + (size_t)(16 + ml) * DD + col);
      a0l = (bf16x8){0, 0, 0, 0, 0, 0, 0, 0};
      a1l = a0l;
    }
#pragma unroll
    for (int nt = 0; nt < 8; ++nt) {
      const size_t bo = ((size_t)(kt * 8 + nt) * 64 + lane) * 8;
      bf16x8 bh = *(const bf16x8*)(whi + bo);
      bf16x8 bl = *(const bf16x8*)(wlo + bo);
      acc[0][nt] = __builtin_amdgcn_mfma_f32_16x16x32_bf16(a0h, bh, acc[0][nt], 0, 0, 0);
      acc[1][nt] = __builtin_amdgcn_mfma_f32_16x16x32_bf16(a1h, bh, acc[1][nt], 0, 0, 0);
      acc[0][nt] = __builtin_amdgcn_mfma_f32_16x16x32_bf16(a0h, bl, acc[0][nt], 0, 0, 0);
      acc[1][nt] = __builtin_amdgcn_mfma_f32_16x16x32_bf16(a1h, bl, acc[1][nt], 0, 0, 0);
      acc[0][nt] = __builtin_amdgcn_mfma_f32_16x16x32_bf16(a0l, bh, acc[0][nt], 0, 0, 0);
      acc[1][nt] = __builtin_amdgcn_mfma_f32_16x16x32_bf16(a1l, bh, acc[1][nt], 0, 0, 0);
    }
  }

  // bias + relu, then normalize capsules IN PLACE (acc becomes zhat).
#pragma unroll
  for (int nt = 0; nt < 8; ++nt) {
    const float bv = isf32 ? ((const float*)b1)[nt * 16 + ml]
                           : bf16bits_to_f32(((const unsigned short*)b1)[nt * 16 + ml]);
#pragma unroll
    for (int mt = 0; mt < 2; ++mt)
#pragma unroll
      for (int r = 0; r < 4; ++r) acc[mt][nt][r] = fmaxf(acc[mt][nt][r] + bv, 0.f);
  }
#pragma unroll
  for (int mt = 0; mt < 2; ++mt)
#pragma unroll
    for (int r = 0; r < 4; ++r)
#pragma unroll
      for (int nt = 0; nt < 8; ++nt) {
        float ss = sum16(acc[mt][nt][r] * acc[mt][nt][r]);
        acc[mt][nt][r] *= 1.f / fmaxf(sqrtf(ss), 1e-12f);
      }

  // ---- iter 0: u = (1/8) sum_n zhat_n + zs ; normalize ---------------------
  float u[8];
#pragma unroll
  for (int nt = 0; nt < 8; ++nt) {
    float t = acc[0][nt][0] + acc[0][nt][1] + acc[0][nt][2] + acc[0][nt][3] +
              acc[1][nt][0] + acc[1][nt][1] + acc[1][nt][2] + acc[1][nt][3];
    t += __shfl_xor(t, 16);
    t += __shfl_xor(t, 32);
    u[nt] = t * 0.125f + zs[nt];
  }
#pragma unroll
  for (int nt = 0; nt < 8; ++nt) {
    float ss = sum16(u[nt] * u[nt]);
    u[nt] *= 1.f / fmaxf(sqrtf(ss), 1e-12f);
  }

  // ---- iters 1,2: fused logits/softmax/weighted-sum (p never stored) -------
#pragma unroll
  for (int it = 1; it < 3; ++it) {
    float unew[8];
#pragma unroll
    for (int nt = 0; nt < 8; ++nt) unew[nt] = 0.f;
#pragma unroll
    for (int mt = 0; mt < 2; ++mt)
#pragma unroll
      for (int r = 0; r < 4; ++r) {
        // |logit| <= 1 (both unit per capsule): exp safe without max-subtract.
        float e[8];
        float s = 0.f;
#pragma unroll
        for (int nt = 0; nt < 8; ++nt) {
          float l = sum16(acc[mt][nt][r] * u[nt]);
          e[nt] = __expf(l);
          s += e[nt];
        }
        const float inv = 1.f / s;
#pragma unroll
        for (int nt = 0; nt < 8; ++nt)
          unew[nt] = fmaf(e[nt] * inv, acc[mt][nt][r], unew[nt]);
      }
#pragma unroll
    for (int nt = 0; nt < 8; ++nt) {
      float t = unew[nt];
      t += __shfl_xor(t, 16);
      t += __shfl_xor(t, 32);
      u[nt] = t + zs[nt];
    }
    if (it < 2) {
#pragma unroll
      for (int nt = 0; nt < 8; ++nt) {
        float ss = sum16(u[nt] * u[nt]);
        u[nt] *= 1.f / fmaxf(sqrtf(ss), 1e-12f);
      }
    }
  }

  // ---- output: relu(u); q==0 lanes cover all 128 cols ----------------------
  if (q == 0) {
#pragma unroll
    for (int nt = 0; nt < 8; ++nt) {
      float r = (u[nt] < 0.f) ? 0.f : u[nt];
      const size_t o = bs * DD + nt * 16 + ml;
      if (isf32) {
        ((float*)out)[o] = r;
      } else {
        unsigned int xb = __float_as_uint(r);
        ((unsigned short*)out)[o] =
            (unsigned short)((xb + 0x7fffu + ((xb >> 16) & 1u)) >> 16);
      }
    }
  }
}

extern "C" void kernel_launch(void* const* d_in, const int* in_sizes, int n_in,
                              void* d_out, int out_size, void* d_ws, size_t ws_size,
                              hipStream_t stream) {
  (void)in_sizes; (void)n_in; (void)out_size; (void)ws_size;
  const void* selfv = d_in[0];
  const void* neighv = d_in[1];
  const void* w1 = d_in[2];
  const void* b1 = d_in[3];
  int* flag = (int*)d_ws;
  unsigned short* whi = (unsigned short*)((char*)d_ws + 64);
  unsigned short* wlo = (unsigned short*)((char*)d_ws + 64 + 32768);

  detect_kernel<<<1, 64, 0, stream>>>((const unsigned short*)w1, flag);
  swizzle_w_kernel<<<64, 256, 0, stream>>>(w1, flag, whi, wlo);
  selfz_kernel<<<512, 64, 0, stream>>>(selfv, whi, wlo, b1, d_out, flag);
  routing_kernel<<<8192, 64, 0, stream>>>(neighv, whi, wlo, b1, d_out, flag);
}